// Round 10
// baseline (117.141 us; speedup 1.0000x reference)
//
#include <hip/hip_runtime.h>
#include <hip/hip_bf16.h>

// SupCon loss, N=8192, D=128, T=0.1.
// R9: TWO nodes.
//   1) norm_csum (R5-proven): per-class ballot-scan; normalize member rows,
//      LDS class-sum, per-row cd/sd/cm1; zeroes se_acc and done.
//   2) main_kernel: flat wave-level triangular jobs (R8) + PAIRWISE B-PREFETCH
//      (b0/b1, next tile's loads issued before current tile's MFMA consumes) +
//      fence-free last-block finalize: all se_acc writes are device-scope
//      atomics (coherent at L2 home); __syncthreads drains vmcnt before the
//      done-increment; last block reads se_acc via agent-scope atomic loads.
//      No __threadfence (R7's per-block fence = 2080 L2 writebacks = +110us).
//
// Math: loss_i = (cm1_i*lse_i - 10*(cd_i - sd_i))/(cm1_i+tiny)
//   lse_i = 10 + ln(sum_{j!=i} e^{s_ij-10})  (constant shift exact; s<=10)
//   cd_i = x_i . classsum[lab_i], sd_i = x_i . x_i (bf16-rounded, matches MFMA)
//   Diagonal excluded in-kernel (J==I tile masks c==row).
//   Symmetry: tile (I,J): J>I feeds rows AND cols; J==I rows only.

typedef __bf16 bf16_t;
typedef __bf16 bf16x2 __attribute__((ext_vector_type(2)));
typedef __bf16 bf16x8 __attribute__((ext_vector_type(8)));
typedef float f32x16 __attribute__((ext_vector_type(16)));

#define NN 8192
#define DIM 128
#define NB 256                    // 32-row bands
#define SEGS 32                   // segments per band -> 8192 wave-jobs
#define NBLK (NB * SEGS / 4)      // 2048 blocks
#define SMALL_VAL 1.17549435e-38f
#define L2E10 14.4269504089f      // 10*log2(e)
#define LN2 0.69314718056f

// Swizzle: X[row][d] at (row>>5)*4096 + (d>>4)*512 + ((d>>3)&1)*256 + (row&31)*8 + (d&7)
// Lane l holds dims (2l,2l+1): f=l>>3, hh=(l>>2)&1, j=(l&3)*2 (pair contiguous).
__device__ inline size_t swz(int row, int lane) {
    int f = lane >> 3, hh = (lane >> 2) & 1, j = (lane & 3) << 1;
    return ((size_t)(row >> 5) * 4096) + f * 512 + hh * 256 + (row & 31) * 8 + j;
}

// --- 1: fused normalize + class-sum + per-row finalize scalars ---
__global__ __launch_bounds__(256) void norm_csum(const float* __restrict__ emb,
                                                 const int* __restrict__ labels,
                                                 bf16_t* __restrict__ xsw,
                                                 float* __restrict__ cd_arr,
                                                 float* __restrict__ sd_arr,
                                                 float* __restrict__ cm1_arr,
                                                 float* __restrict__ se_acc,
                                                 int* __restrict__ done) {
    __shared__ float cs[DIM];
    __shared__ int rowlist[96];
    __shared__ int nrows;
    int cls = blockIdx.x;                      // 1024 blocks; labels < 1000
    int wv = threadIdx.x >> 6, lane = threadIdx.x & 63;
    if (threadIdx.x < DIM) cs[threadIdx.x] = 0.f;
    if (threadIdx.x == 0) nrows = 0;
    if (threadIdx.x < 8) se_acc[cls * 8 + threadIdx.x] = 0.f;   // zero all 8192
    if (cls == 0 && threadIdx.x == 0) *done = 0;
    __syncthreads();

    float s0 = 0.f, s1 = 0.f;
    const int4* lab4 = (const int4*)(labels + wv * 2048);       // wave's quarter
#pragma unroll
    for (int it = 0; it < 8; ++it) {
        int4 l = lab4[it * 64 + lane];
        int base = wv * 2048 + it * 256;
#pragma unroll
        for (int cmp = 0; cmp < 4; ++cmp) {
            int li = (cmp == 0) ? l.x : (cmp == 1) ? l.y : (cmp == 2) ? l.z : l.w;
            unsigned long long m = __ballot(li == cls);
            while (m) {                         // wave-uniform; ~2 rows/wave avg
                int bb = __builtin_ctzll(m);
                m &= m - 1;
                int row = base + 4 * bb + cmp;
                float2 v = ((const float2*)emb)[row * 64 + lane];
                float ss = fmaf(v.x, v.x, v.y * v.y);
#pragma unroll
                for (int mm = 1; mm < 64; mm <<= 1) ss += __shfl_xor(ss, mm, 64);
                float inv = 1.0f / fmaxf(sqrtf(ss), 1e-12f);
                bf16x2 o; o.x = (bf16_t)(v.x * inv); o.y = (bf16_t)(v.y * inv);
                *(bf16x2*)(xsw + swz(row, lane)) = o;
                s0 += (float)o.x; s1 += (float)o.y;     // bf16-rounded, matches MFMA
                if (lane == 0) {
                    int idx = atomicAdd(&nrows, 1);
                    if (idx < 96) rowlist[idx] = row;
                }
            }
        }
    }
    atomicAdd(&cs[2 * lane], s0);
    atomicAdd(&cs[2 * lane + 1], s1);
    __syncthreads();
    int n = nrows;
    for (int k = wv; k < n; k += 4) {          // per-row cd/sd
        int row = rowlist[k];
        bf16x2 xv = *(const bf16x2*)(xsw + swz(row, lane));
        float x0 = (float)xv.x, x1 = (float)xv.y;
        float cdp = fmaf(x0, cs[2 * lane], x1 * cs[2 * lane + 1]);
        float sdp = fmaf(x0, x0, x1 * x1);
#pragma unroll
        for (int mm = 1; mm < 64; mm <<= 1) {
            cdp += __shfl_xor(cdp, mm, 64);
            sdp += __shfl_xor(sdp, mm, 64);
        }
        if (lane == 0) {
            cd_arr[row] = cdp; sd_arr[row] = sdp; cm1_arr[row] = (float)(n - 1);
        }
    }
}

#define LDB(dst, J_) do {                                                        \
    const bf16_t* p_ = xsw + (size_t)(J_) * 4096 + laneoff;                      \
    _Pragma("unroll")                                                            \
    for (int f_ = 0; f_ < 8; ++f_) dst[f_] = *(const bf16x8*)(p_ + f_ * 512);    \
} while (0)

#define TILE(bb, J_) do {                                                        \
    f32x16 acc_;                                                                 \
    _Pragma("unroll")                                                            \
    for (int r_ = 0; r_ < 16; ++r_) acc_[r_] = 0.f;                              \
    _Pragma("unroll")                                                            \
    for (int f_ = 0; f_ < 8; ++f_)                                               \
        acc_ = __builtin_amdgcn_mfma_f32_32x32x16_bf16(a[f_], bb[f_], acc_, 0, 0, 0); \
    if ((J_) == I) {                       /* diagonal tile: rows only, mask diag */ \
        _Pragma("unroll")                                                        \
        for (int r_ = 0; r_ < 16; ++r_) {                                        \
            bool isd_ = c == ((r_ & 3) + 8 * (r_ >> 2) + 4 * h);                 \
            se[r_] += isd_ ? 0.f                                                 \
                           : __builtin_amdgcn_exp2f(fmaf(acc_[r_], L2E10, -L2E10)); \
        }                                                                        \
    } else {                               /* off-diag: rows + transpose cols */ \
        float c0_=0.f, c1_=0.f, c2_=0.f, c3_=0.f;                                \
        _Pragma("unroll")                                                        \
        for (int r_ = 0; r_ < 16; ++r_) {                                        \
            float e_ = __builtin_amdgcn_exp2f(fmaf(acc_[r_], L2E10, -L2E10));    \
            se[r_] += e_;                                                        \
            if ((r_&3)==0) c0_+=e_; else if ((r_&3)==1) c1_+=e_;                 \
            else if ((r_&3)==2) c2_+=e_; else c3_+=e_;                           \
        }                                                                        \
        float v_ = (c0_ + c1_) + (c2_ + c3_);                                    \
        v_ += __shfl_xor(v_, 32, 64);                                            \
        if (h == 0) atomicAdd(&se_acc[(J_) * 32 + c], v_);                       \
    }                                                                            \
} while (0)

// --- 2: flat wave-job triangular Gram + pairwise B prefetch + fused finalize.
// Wave wid -> band I = wid>>5, seg s = wid&31: tiles J in
// [I + (NT*s>>5), I + (NT*(s+1)>>5)), NT = 256-I.
// C layout (m74/m101): col = lane&31, row = (r&3) + 8*(r>>2) + 4*(lane>>5).
__global__ __launch_bounds__(256, 3) void main_kernel(const bf16_t* __restrict__ xsw,
                                                      const float* __restrict__ cd_arr,
                                                      const float* __restrict__ sd_arr,
                                                      const float* __restrict__ cm1_arr,
                                                      float* __restrict__ se_acc,
                                                      int* __restrict__ done,
                                                      float* __restrict__ out) {
    __shared__ float part[4];
    __shared__ int amlast;
    int wid  = blockIdx.x * 4 + (threadIdx.x >> 6);
    int lane = threadIdx.x & 63;
    int I = wid >> 5, s = wid & 31;
    int NT = NB - I;
    int t0 = (NT * s) >> 5, t1 = (NT * (s + 1)) >> 5;
    int c = lane & 31, h = lane >> 5;
    int laneoff = h * 256 + c * 8;

    if (t0 < t1) {                             // wave-uniform; empty segs skip work
        const bf16_t* abase = xsw + (size_t)I * 4096 + laneoff;
        bf16x8 a[8];
#pragma unroll
        for (int f = 0; f < 8; ++f) a[f] = *(const bf16x8*)(abase + f * 512);

        float se[16];
#pragma unroll
        for (int r = 0; r < 16; ++r) se[r] = 0.f;

        bf16x8 b0[8], b1[8];
        int t = t0;
        LDB(b0, I + t);
        while (t + 1 < t1) {                   // pairwise: prefetch hides L2 latency
            LDB(b1, I + t + 1);
            TILE(b0, I + t);
            if (t + 2 < t1) LDB(b0, I + t + 2);
            TILE(b1, I + t + 1);
            t += 2;
        }
        if (t < t1) TILE(b0, I + t);

        // row-side: reduce se[r] over the 32 c-lanes of each half, flush once
#pragma unroll
        for (int r = 0; r < 16; ++r) {
            float vv = se[r];
#pragma unroll
            for (int m = 1; m < 32; m <<= 1) vv += __shfl_xor(vv, m, 64);
            se[r] = vv;
        }
        if (c == 0) {
            int rowbase = I * 32 + 4 * h;
#pragma unroll
            for (int r = 0; r < 16; ++r)
                atomicAdd(&se_acc[rowbase + (r & 3) + 8 * (r >> 2)], se[r]);
        }
    }

    // --- completion: __syncthreads drains this block's vmcnt (atomics complete
    // at coherent point) BEFORE the done-increment; no fence needed.
    __syncthreads();
    if (threadIdx.x == 0) amlast = (atomicAdd(done, 1) == NBLK - 1);
    __syncthreads();
    if (!amlast) return;

    // last block: finalize. se_acc read with agent-scope atomic loads (coherent).
    float lsum = 0.f;
    for (int i = threadIdx.x; i < NN; i += 256) {
        float sev = __hip_atomic_load(&se_acc[i], __ATOMIC_RELAXED,
                                      __HIP_MEMORY_SCOPE_AGENT);
        float sd = sd_arr[i], cd = cd_arr[i], cm1 = cm1_arr[i];
        sev = fmaxf(sev, 1e-30f);
        float lse = fmaf(__builtin_amdgcn_logf(sev), LN2, 10.f);
        lsum += (cm1 * lse - 10.f * (cd - sd)) / (cm1 + SMALL_VAL);
    }
#pragma unroll
    for (int m = 1; m < 64; m <<= 1) lsum += __shfl_xor(lsum, m, 64);
    if (lane == 0) part[threadIdx.x >> 6] = lsum;
    __syncthreads();
    if (threadIdx.x == 0) *out = part[0] + part[1] + part[2] + part[3];
}

extern "C" void kernel_launch(void* const* d_in, const int* in_sizes, int n_in,
                              void* d_out, int out_size, void* d_ws, size_t ws_size,
                              hipStream_t stream) {
    const float* emb  = (const float*)d_in[0];
    const int* labels = (const int*)d_in[1];

    char* ws = (char*)d_ws;
    bf16_t* xsw = (bf16_t*)ws;                          // 2 MB swizzled normalized X
    float* se   = (float*)(ws + (size_t)NN * DIM * 2);  // 32 KB
    float* cd   = se + NN;
    float* sd   = cd + NN;
    float* cm1  = sd + NN;
    int*   done = (int*)(cm1 + NN);

    norm_csum<<<1024, 256, 0, stream>>>(emb, labels, xsw, cd, sd, cm1, se, done);
    main_kernel<<<NBLK, 256, 0, stream>>>(xsw, cd, sd, cm1, se, done, (float*)d_out);
}

// Round 11
// 99.424 us; speedup vs baseline: 1.1782x; 1.1782x over previous
//
#include <hip/hip_runtime.h>
#include <hip/hip_bf16.h>

// SupCon loss, N=8192, D=128, T=0.1.
// R10: 3 nodes; FULL-SQUARE main (no triangle symmetry).
//   Rationale (R9 counters): col-side per-tile device-scope atomics (1.2M) were
//   the stall (WRITE 8MB, both pipes <15%). Full square doubles MFMA (idle pipe,
//   6% busy) but makes ALL contributions row-side -> se[16] accumulates in
//   registers across the wave's whole 16-tile column sweep, ONE flush per wave
//   (131K atomics total, 9x fewer). Perfectly uniform work: 4096 waves x 16
//   tiles. Segment-major grid: 64 consecutive blocks share one 32KB B-segment.
//   1) norm_csum (R5-proven), 2) main, 3) finalize (elementwise).
//
// Math: loss_i = (cm1_i*lse_i - 10*(cd_i - sd_i))/(cm1_i+tiny)
//   lse_i = 10 + ln(sum_{j!=i} e^{s_ij-10})  (constant shift exact; s<=10)
//   cd_i = x_i . classsum[lab_i], sd_i = x_i . x_i (bf16-rounded, matches MFMA)
//   Diagonal excluded in-kernel (jt==I tile masks c==row); full row sweep
//   covers all j naturally — no transpose bookkeeping, no diag subtraction.

typedef __bf16 bf16_t;
typedef __bf16 bf16x2 __attribute__((ext_vector_type(2)));
typedef __bf16 bf16x8 __attribute__((ext_vector_type(8)));
typedef float f32x16 __attribute__((ext_vector_type(16)));

#define NN 8192
#define DIM 128
#define NB 256                    // 32-row bands
#define SEGS 16                   // column segments (16 tiles each)
#define SMALL_VAL 1.17549435e-38f
#define L2E10 14.4269504089f      // 10*log2(e)
#define LN2 0.69314718056f

// Swizzle: X[row][d] at (row>>5)*4096 + (d>>4)*512 + ((d>>3)&1)*256 + (row&31)*8 + (d&7)
// Lane l holds dims (2l,2l+1): f=l>>3, hh=(l>>2)&1, j=(l&3)*2 (pair contiguous).
__device__ inline size_t swz(int row, int lane) {
    int f = lane >> 3, hh = (lane >> 2) & 1, j = (lane & 3) << 1;
    return ((size_t)(row >> 5) * 4096) + f * 512 + hh * 256 + (row & 31) * 8 + j;
}

// --- 1: fused normalize + class-sum + per-row finalize scalars (R5-proven) ---
__global__ __launch_bounds__(256) void norm_csum(const float* __restrict__ emb,
                                                 const int* __restrict__ labels,
                                                 bf16_t* __restrict__ xsw,
                                                 float* __restrict__ cd_arr,
                                                 float* __restrict__ sd_arr,
                                                 float* __restrict__ cm1_arr,
                                                 float* __restrict__ se_acc,
                                                 float* __restrict__ out) {
    __shared__ float cs[DIM];
    __shared__ int rowlist[96];
    __shared__ int nrows;
    int cls = blockIdx.x;                      // 1024 blocks; labels < 1000
    int wv = threadIdx.x >> 6, lane = threadIdx.x & 63;
    if (threadIdx.x < DIM) cs[threadIdx.x] = 0.f;
    if (threadIdx.x == 0) nrows = 0;
    if (threadIdx.x < 8) se_acc[cls * 8 + threadIdx.x] = 0.f;   // zero all 8192
    if (cls == 0 && threadIdx.x == 0) *out = 0.f;
    __syncthreads();

    float s0 = 0.f, s1 = 0.f;
    const int4* lab4 = (const int4*)(labels + wv * 2048);       // wave's quarter
#pragma unroll
    for (int it = 0; it < 8; ++it) {
        int4 l = lab4[it * 64 + lane];
        int base = wv * 2048 + it * 256;
#pragma unroll
        for (int cmp = 0; cmp < 4; ++cmp) {
            int li = (cmp == 0) ? l.x : (cmp == 1) ? l.y : (cmp == 2) ? l.z : l.w;
            unsigned long long m = __ballot(li == cls);
            while (m) {                         // wave-uniform; ~2 rows/wave avg
                int bb = __builtin_ctzll(m);
                m &= m - 1;
                int row = base + 4 * bb + cmp;
                float2 v = ((const float2*)emb)[row * 64 + lane];
                float ss = fmaf(v.x, v.x, v.y * v.y);
#pragma unroll
                for (int mm = 1; mm < 64; mm <<= 1) ss += __shfl_xor(ss, mm, 64);
                float inv = 1.0f / fmaxf(sqrtf(ss), 1e-12f);
                bf16x2 o; o.x = (bf16_t)(v.x * inv); o.y = (bf16_t)(v.y * inv);
                *(bf16x2*)(xsw + swz(row, lane)) = o;
                s0 += (float)o.x; s1 += (float)o.y;     // bf16-rounded, matches MFMA
                if (lane == 0) {
                    int idx = atomicAdd(&nrows, 1);
                    if (idx < 96) rowlist[idx] = row;
                }
            }
        }
    }
    atomicAdd(&cs[2 * lane], s0);
    atomicAdd(&cs[2 * lane + 1], s1);
    __syncthreads();
    int n = nrows;
    for (int k = wv; k < n; k += 4) {          // per-row cd/sd
        int row = rowlist[k];
        bf16x2 xv = *(const bf16x2*)(xsw + swz(row, lane));
        float x0 = (float)xv.x, x1 = (float)xv.y;
        float cdp = fmaf(x0, cs[2 * lane], x1 * cs[2 * lane + 1]);
        float sdp = fmaf(x0, x0, x1 * x1);
#pragma unroll
        for (int mm = 1; mm < 64; mm <<= 1) {
            cdp += __shfl_xor(cdp, mm, 64);
            sdp += __shfl_xor(sdp, mm, 64);
        }
        if (lane == 0) {
            cd_arr[row] = cdp; sd_arr[row] = sdp; cm1_arr[row] = (float)(n - 1);
        }
    }
}

// --- 2: full-square main. Block b (1024): segment s = b>>6 (16 tiles of 32
// cols), band I = (b&63)*4 + wv. Wave sweeps its 16 tiles, se[16] in registers,
// ONE atomic flush at the end. Zero LDS, zero __syncthreads, no col-side work.
// C layout (m74/m101): col = lane&31, row = (r&3) + 8*(r>>2) + 4*(lane>>5).
__global__ __launch_bounds__(256, 4) void main_kernel(const bf16_t* __restrict__ xsw,
                                                      float* __restrict__ se_acc) {
    int wv = threadIdx.x >> 6, lane = threadIdx.x & 63;
    int s = blockIdx.x >> 6;                   // 0..15: column segment
    int I = (blockIdx.x & 63) * 4 + wv;        // 0..255: row band
    int c = lane & 31, h = lane >> 5;
    int laneoff = h * 256 + c * 8;

    const bf16_t* abase = xsw + (size_t)I * 4096 + laneoff;
    bf16x8 a[8];
#pragma unroll
    for (int f = 0; f < 8; ++f) a[f] = *(const bf16x8*)(abase + f * 512);

    float se[16];
#pragma unroll
    for (int r = 0; r < 16; ++r) se[r] = 0.f;

    int j0 = s * 16;
#pragma unroll 2
    for (int jt = j0; jt < j0 + 16; ++jt) {
        const bf16_t* bbase = xsw + (size_t)jt * 4096 + laneoff;
        bf16x8 b[8];
#pragma unroll
        for (int f = 0; f < 8; ++f) b[f] = *(const bf16x8*)(bbase + f * 512);
        f32x16 acc;
#pragma unroll
        for (int r = 0; r < 16; ++r) acc[r] = 0.f;
#pragma unroll
        for (int f = 0; f < 8; ++f)
            acc = __builtin_amdgcn_mfma_f32_32x32x16_bf16(a[f], b[f], acc, 0, 0, 0);

        if (jt == I) {                         // diagonal tile (wave-uniform)
#pragma unroll
            for (int r = 0; r < 16; ++r) {
                bool isdiag = c == ((r & 3) + 8 * (r >> 2) + 4 * h);
                se[r] += isdiag ? 0.f
                                : __builtin_amdgcn_exp2f(fmaf(acc[r], L2E10, -L2E10));
            }
        } else {
#pragma unroll
            for (int r = 0; r < 16; ++r)
                se[r] += __builtin_amdgcn_exp2f(fmaf(acc[r], L2E10, -L2E10));
        }
    }

    // single flush: reduce se[r] over the 32 c-lanes of each half
#pragma unroll
    for (int r = 0; r < 16; ++r) {
        float vv = se[r];
#pragma unroll
        for (int m = 1; m < 32; m <<= 1) vv += __shfl_xor(vv, m, 64);
        se[r] = vv;
    }
    if (c == 0) {
        int rowbase = I * 32 + 4 * h;
#pragma unroll
        for (int r = 0; r < 16; ++r)
            atomicAdd(&se_acc[rowbase + (r & 3) + 8 * (r >> 2)], se[r]);
    }
}

// --- 3: elementwise finalize (diag already excluded in main) ---
__global__ __launch_bounds__(256) void finalize_kernel(const float* __restrict__ se_acc,
                                                       const float* __restrict__ cd_arr,
                                                       const float* __restrict__ sd_arr,
                                                       const float* __restrict__ cm1_arr,
                                                       float* __restrict__ out) {
    __shared__ float part[4];
    int i = blockIdx.x * 256 + threadIdx.x;
    float sd = sd_arr[i], cd = cd_arr[i], cm1 = cm1_arr[i];
    float sev  = fmaxf(se_acc[i], 1e-30f);
    float lse  = fmaf(__builtin_amdgcn_logf(sev), LN2, 10.f);
    float loss = (cm1 * lse - 10.f * (cd - sd)) / (cm1 + SMALL_VAL);
#pragma unroll
    for (int m = 1; m < 64; m <<= 1) loss += __shfl_xor(loss, m, 64);
    int wv = threadIdx.x >> 6;
    if ((threadIdx.x & 63) == 0) part[wv] = loss;
    __syncthreads();
    if (threadIdx.x == 0) atomicAdd(out, part[0] + part[1] + part[2] + part[3]);
}

extern "C" void kernel_launch(void* const* d_in, const int* in_sizes, int n_in,
                              void* d_out, int out_size, void* d_ws, size_t ws_size,
                              hipStream_t stream) {
    const float* emb  = (const float*)d_in[0];
    const int* labels = (const int*)d_in[1];

    char* ws = (char*)d_ws;
    bf16_t* xsw = (bf16_t*)ws;                          // 2 MB swizzled normalized X
    float* se   = (float*)(ws + (size_t)NN * DIM * 2);  // 32 KB
    float* cd   = se + NN;
    float* sd   = cd + NN;
    float* cm1  = sd + NN;

    norm_csum<<<1024, 256, 0, stream>>>(emb, labels, xsw, cd, sd, cm1, se, (float*)d_out);
    main_kernel<<<NB / 4 * SEGS, 256, 0, stream>>>(xsw, se);
    finalize_kernel<<<NN / 256, 256, 0, stream>>>(se, cd, sd, cm1, (float*)d_out);
}